// Round 10
// baseline (269.566 us; speedup 1.0000x reference)
//
#include <hip/hip_runtime.h>
#include <math.h>

#define NROWS 4096
#define HIDN  512
#define H1N   256
#define H2N   1024
#define NHEAD 4
#define KDIM  256
#define HALFD 128
#define SUBS  512
#define KNN   32

typedef _Float16 f16x8 __attribute__((ext_vector_type(8)));
typedef _Float16 f16x4v __attribute__((ext_vector_type(4)));
typedef float f32x4  __attribute__((ext_vector_type(4)));

// ---------------- DPP wave reduction helpers ----------------
template<int C>
__device__ __forceinline__ unsigned dpp_umax(unsigned x) {
    unsigned m = (unsigned)__builtin_amdgcn_update_dpp((int)x, (int)x, C, 0xf, 0xf, false);
    return x > m ? x : m;
}
__device__ __forceinline__ unsigned wave_umax_bcast(unsigned x) {
    x = dpp_umax<0x111>(x);
    x = dpp_umax<0x112>(x);
    x = dpp_umax<0x114>(x);
    x = dpp_umax<0x118>(x);
    x = dpp_umax<0x142>(x);
    x = dpp_umax<0x143>(x);
    return (unsigned)__builtin_amdgcn_readlane((int)x, 63);
}
template<int C>
__device__ __forceinline__ float dpp_fadd(float x) {
    int m = __builtin_amdgcn_update_dpp(0, __float_as_int(x), C, 0xf, 0xf, true);
    return x + __int_as_float(m);
}
__device__ __forceinline__ float wave_fsum_bcast(float x) {
    x = dpp_fadd<0x111>(x);
    x = dpp_fadd<0x112>(x);
    x = dpp_fadd<0x114>(x);
    x = dpp_fadd<0x118>(x);
    x = dpp_fadd<0x142>(x);
    x = dpp_fadd<0x143>(x);
    return __int_as_float(__builtin_amdgcn_readlane(__float_as_int(x), 63));
}

template<int IB>
__device__ __forceinline__ unsigned pack_key(float v, int j) {
    unsigned b = __float_as_uint(v);
    unsigned x = (unsigned)((int)b >> 31) | 0x80000000u;
    unsigned k = b ^ x;
    constexpr unsigned LM = (1u << IB) - 1u;
    return (k & ~LM) | (LM - (unsigned)j);
}
template<int IB>
__device__ __forceinline__ float dec_key(unsigned k) {
    constexpr unsigned LM = (1u << IB) - 1u;
    unsigned kv = k & ~LM;
    unsigned x = (~(unsigned)((int)kv >> 31)) | 0x80000000u;
    return __uint_as_float(kv ^ x);
}

__device__ __forceinline__ void slot_to_ij(int s, int& io, int& jo) {
    constexpr int O[32] = {0,32,48,58,66,72,77,81,85,88,91,93,95,97,99,101,
                           103,104,105,106,107,108,109,110,111,112,113,114,115,116,117,118};
    int ii = 0, oo = 0;
    #pragma unroll
    for (int k = 1; k < 32; ++k) {
        bool ge = (s >= O[k]);
        ii += ge ? 1 : 0;
        oo = ge ? O[k] : oo;
    }
    io = ii; jo = s - oo;
}

// ---------------- fp32 -> fp16 convert ----------------
__global__ __launch_bounds__(256)
void cvt_f16(const float* __restrict__ in, _Float16* __restrict__ out)
{
    int i = (blockIdx.x * 256 + threadIdx.x) * 4;
    float4 v = *(const float4*)&in[i];
    f16x4v o = {(_Float16)v.x, (_Float16)v.y, (_Float16)v.z, (_Float16)v.w};
    *(f16x4v*)&out[i] = o;
}

// ---------------- fp16 MFMA GEMM: C = act(A(M,K) @ B(N,K)^T + bias), fp16 out ----------------
template<int BN, int ACT>
__global__ __launch_bounds__(256)
void gemm_f16(const _Float16* __restrict__ A, const _Float16* __restrict__ B,
              const float* __restrict__ bias, _Float16* __restrict__ C,
              int K, int lda, int ldb, int ldc)
{
    constexpr int WR = (BN == 128) ? 2 : 4;
    constexpr int WM = 128 / WR;
    constexpr int MT = WM / 16;
    constexpr int NT = 4;

    __shared__ _Float16 As[128 * 64];
    __shared__ _Float16 Bs[BN * 64];

    const int t    = threadIdx.x;
    const int m0   = blockIdx.x * 128, n0 = blockIdx.y * BN;
    const int lane = t & 63, wv = t >> 6;
    const int wr   = (BN == 128) ? (wv >> 1) : wv;
    const int wc   = (BN == 128) ? (wv & 1) : 0;
    const int sr   = t >> 3;
    const int sce  = (t & 7) * 8;
    const int swz  = sce * 2;

    const f32x4 fz = {0.f, 0.f, 0.f, 0.f};
    f32x4 acc[MT][NT];
    #pragma unroll
    for (int mt = 0; mt < MT; ++mt)
        #pragma unroll
        for (int nt = 0; nt < NT; ++nt) acc[mt][nt] = fz;

    for (int kb = 0; kb < K; kb += 64) {
        #pragma unroll
        for (int i = 0; i < 4; ++i) {
            int r = sr + 32 * i;
            uint4 v = *(const uint4*)&A[(size_t)(m0 + r) * lda + kb + sce];
            *(uint4*)((char*)As + r * 128 + (swz ^ ((r & 7) << 4))) = v;
        }
        #pragma unroll
        for (int i = 0; i < BN / 32; ++i) {
            int r = sr + 32 * i;
            uint4 v = *(const uint4*)&B[(size_t)(n0 + r) * ldb + kb + sce];
            *(uint4*)((char*)Bs + r * 128 + (swz ^ ((r & 7) << 4))) = v;
        }
        __syncthreads();
        #pragma unroll
        for (int ks = 0; ks < 2; ++ks) {
            const int kbyte = ks * 64 + (lane >> 4) * 16;
            f16x8 ah[MT], bf[NT];
            #pragma unroll
            for (int mt = 0; mt < MT; ++mt) {
                int r = wr * WM + mt * 16 + (lane & 15);
                ah[mt] = *(const f16x8*)((const char*)As + r * 128 + (kbyte ^ ((r & 7) << 4)));
            }
            #pragma unroll
            for (int nt = 0; nt < NT; ++nt) {
                int r = wc * 64 + nt * 16 + (lane & 15);
                bf[nt] = *(const f16x8*)((const char*)Bs + r * 128 + (kbyte ^ ((r & 7) << 4)));
            }
            #pragma unroll
            for (int mt = 0; mt < MT; ++mt)
                #pragma unroll
                for (int nt = 0; nt < NT; ++nt)
                    acc[mt][nt] = __builtin_amdgcn_mfma_f32_16x16x32_f16(ah[mt], bf[nt], acc[mt][nt], 0, 0, 0);
        }
        __syncthreads();
    }

    #pragma unroll
    for (int mt = 0; mt < MT; ++mt) {
        #pragma unroll
        for (int nt = 0; nt < NT; ++nt) {
            int col = n0 + wc * 64 + nt * 16 + (lane & 15);
            float bz = bias[col];
            #pragma unroll
            for (int j = 0; j < 4; ++j) {
                int row = m0 + wr * WM + mt * 16 + (lane >> 4) * 4 + j;
                float v = acc[mt][nt][j] + bz;
                if (ACT) v = v > 0.f ? v : expm1f(v);
                C[(size_t)row * ldc + col] = (_Float16)v;
            }
        }
    }
}

// ---------------- BatchNorm stats (fp16 h2) ----------------
__global__ __launch_bounds__(256)
void bn_partial_h(const _Float16* __restrict__ h2f, float* __restrict__ part)
{
    int col = blockIdx.x * 256 + threadIdx.x;
    int r0  = blockIdx.y * 256;
    float s = 0.f, q = 0.f;
    for (int rr = r0; rr < r0 + 256; ++rr) {
        float v = (float)h2f[(size_t)rr * H2N + col];
        s += v; q += v * v;
    }
    part[(size_t)blockIdx.y * H2N + col] = s;
    part[(size_t)16 * H2N + (size_t)blockIdx.y * H2N + col] = q;
}

__global__ __launch_bounds__(256)
void bn_finalize(const float* __restrict__ part, const float* __restrict__ gamma,
                 const float* __restrict__ beta, float* __restrict__ scale,
                 float* __restrict__ shift)
{
    int col = blockIdx.x * 256 + threadIdx.x;
    float s = 0.f, q = 0.f;
    for (int c = 0; c < 16; ++c) {
        s += part[(size_t)c * H2N + col];
        q += part[(size_t)16 * H2N + (size_t)c * H2N + col];
    }
    float mu  = s * (1.f / NROWS);
    float var = q * (1.f / NROWS) - mu * mu;
    float sc  = gamma[col] / sqrtf(var + 1e-5f);
    scale[col] = sc;
    shift[col] = beta[col] - mu * sc;
}

// ---------------- fold BN affine into keys ----------------
__global__ __launch_bounds__(256)
void keys_prep(const float* __restrict__ keys, const float* __restrict__ scale,
               const float* __restrict__ shift, _Float16* __restrict__ keysp,
               float* __restrict__ biasp)
{
    const int gid  = blockIdx.x * 4 + (threadIdx.x >> 6);   // 0..4095
    const int lane = threadIdx.x & 63;
    const int z    = gid >> 9;
    const float* krow = keys + (size_t)gid * HALFD;
    const int d0 = lane * 2;
    float k0 = krow[d0], k1 = krow[d0 + 1];
    float sc0 = scale[z * HALFD + d0], sc1 = scale[z * HALFD + d0 + 1];
    float sh0 = shift[z * HALFD + d0], sh1 = shift[z * HALFD + d0 + 1];
    _Float16 p0 = (_Float16)(sc0 * k0), p1 = (_Float16)(sc1 * k1);
    unsigned u;
    {
        union { _Float16 h[2]; unsigned u; } cvt;
        cvt.h[0] = p0; cvt.h[1] = p1;
        u = cvt.u;
    }
    *(unsigned*)&keysp[(size_t)gid * HALFD + d0] = u;
    float dot = wave_fsum_bcast(k0 * sh0 + k1 * sh1);
    if (lane == 0) biasp[gid] = dot;
}

// ---------------- Fused score MFMA + phase-1 top-32 ----------------
// grid (NROWS/64, 8 z), 512 threads = 8 waves (2M x 4N). BM=64, BN=512, K=128.
// Epilogue packs score keys into LDS (64 x 513 u32, aliased over As/Bs), then
// each wave extracts top-32 for 8 rows (sorted-8 + DPP umax) -> t_all.
__global__ __launch_bounds__(512)
void score_topk(const _Float16* __restrict__ h2f, const _Float16* __restrict__ keysp,
                const float* __restrict__ biasp, unsigned* __restrict__ t_all)
{
    __shared__ unsigned smem[64 * 513];           // 131328 B
    _Float16* As = (_Float16*)smem;               // [64 x 64] fp16 (during GEMM)
    _Float16* Bs = (_Float16*)smem + 4096;        // [512 x 64] fp16 (during GEMM)

    const int t    = threadIdx.x;
    const int z    = blockIdx.y;
    const int m0   = blockIdx.x * 64;
    const int lane = t & 63, wv = t >> 6;
    const int wr   = wv >> 2, wc = wv & 3;        // 2 waves M x 4 waves N
    const int sr   = t >> 3;                      // 0..63
    const int sce  = (t & 7) * 8;
    const int swz  = sce * 2;

    const _Float16* A = h2f + z * HALFD;                    // lda = H2N
    const _Float16* B = keysp + (size_t)z * SUBS * HALFD;   // (512,128)

    const f32x4 fz = {0.f, 0.f, 0.f, 0.f};
    f32x4 acc[2][8];
    #pragma unroll
    for (int mt = 0; mt < 2; ++mt)
        #pragma unroll
        for (int nt = 0; nt < 8; ++nt) acc[mt][nt] = fz;

    for (int kb = 0; kb < HALFD; kb += 64) {
        {
            uint4 v = *(const uint4*)&A[(size_t)(m0 + sr) * H2N + kb + sce];
            *(uint4*)((char*)As + sr * 128 + (swz ^ ((sr & 7) << 4))) = v;
        }
        #pragma unroll
        for (int i = 0; i < 8; ++i) {
            int r = sr + 64 * i;
            uint4 v = *(const uint4*)&B[(size_t)r * HALFD + kb + sce];
            *(uint4*)((char*)Bs + r * 128 + (swz ^ ((r & 7) << 4))) = v;
        }
        __syncthreads();
        #pragma unroll
        for (int ks = 0; ks < 2; ++ks) {
            const int kbyte = ks * 64 + (lane >> 4) * 16;
            f16x8 af[2], bf[8];
            #pragma unroll
            for (int mt = 0; mt < 2; ++mt) {
                int r = wr * 32 + mt * 16 + (lane & 15);
                af[mt] = *(const f16x8*)((const char*)As + r * 128 + (kbyte ^ ((r & 7) << 4)));
            }
            #pragma unroll
            for (int nt = 0; nt < 8; ++nt) {
                int r = wc * 128 + nt * 16 + (lane & 15);
                bf[nt] = *(const f16x8*)((const char*)Bs + r * 128 + (kbyte ^ ((r & 7) << 4)));
            }
            #pragma unroll
            for (int mt = 0; mt < 2; ++mt)
                #pragma unroll
                for (int nt = 0; nt < 8; ++nt)
                    acc[mt][nt] = __builtin_amdgcn_mfma_f32_16x16x32_f16(af[mt], bf[nt], acc[mt][nt], 0, 0, 0);
        }
        __syncthreads();
    }

    // epilogue: pack score keys into LDS rows (stride 513 words -> conflict-light)
    #pragma unroll
    for (int mt = 0; mt < 2; ++mt) {
        #pragma unroll
        for (int nt = 0; nt < 8; ++nt) {
            int col = wc * 128 + nt * 16 + (lane & 15);
            float bz = biasp[z * SUBS + col];
            #pragma unroll
            for (int j = 0; j < 4; ++j) {
                int row = wr * 32 + mt * 16 + (lane >> 4) * 4 + j;
                smem[row * 513 + col] = pack_key<9>(acc[mt][nt][j] + bz, col);
            }
        }
    }
    __syncthreads();

    // extraction: wave wv handles rows wv*8 .. wv*8+7
    for (int rr8 = 0; rr8 < 8; ++rr8) {
        const int r = wv * 8 + rr8;
        const unsigned* rowp = &smem[r * 513 + lane * 8];
        unsigned k0 = rowp[0], k1 = rowp[1], k2 = rowp[2], k3 = rowp[3];
        unsigned k4 = rowp[4], k5 = rowp[5], k6 = rowp[6], k7 = rowp[7];

        #define CEU(a,b) { unsigned _mx = (a)>(b)?(a):(b); unsigned _mn = (a)>(b)?(b):(a); (a)=_mx; (b)=_mn; }
        CEU(k0,k1) CEU(k2,k3) CEU(k4,k5) CEU(k6,k7)
        CEU(k0,k2) CEU(k1,k3) CEU(k4,k6) CEU(k5,k7)
        CEU(k1,k2) CEU(k5,k6)
        CEU(k0,k4) CEU(k1,k5) CEU(k2,k6) CEU(k3,k7)
        CEU(k2,k4) CEU(k3,k5)
        CEU(k1,k2) CEU(k3,k4) CEU(k5,k6)
        #undef CEU

        unsigned kk = 0;
        #pragma unroll
        for (int rr = 0; rr < KNN; ++rr) {
            unsigned bv = wave_umax_bcast(k0);
            bool win = (k0 == bv);
            k0 = win ? k1 : k0;
            k1 = win ? k2 : k1;
            k2 = win ? k3 : k2;
            k3 = win ? k4 : k3;
            k4 = win ? k5 : k4;
            k5 = win ? k6 : k5;
            k6 = win ? k7 : k6;
            k7 = win ? 0u : k7;
            kk = (lane == rr) ? bv : kk;
        }
        if (lane < KNN)
            t_all[((size_t)(m0 + r) * 8 + z) * KNN + lane] = kk;
    }
}

// ---------------- Combine + softmax + gather ----------------
// Phase 1 is now a 1 KB coalesced t_all load; phases 2/3 proven from R6.
__global__ __launch_bounds__(512)
void topk_gather(const unsigned* __restrict__ t_all,
                 const float* __restrict__ values, float* __restrict__ out)
{
    const int b    = blockIdx.x;
    const int t    = threadIdx.x;
    const int w    = t >> 6;
    const int lane = t & 63;

    __shared__ unsigned Ksh[8][KNN];
    __shared__ float wgt_sh[NHEAD * KNN];
    __shared__ int   idx_sh[NHEAD * KNN];
    __shared__ float4 pacc[4][128];

    // ---- phase 1: load per-task top-32 keys ----
    if (lane < KNN) Ksh[w][lane] = t_all[((size_t)b * 8 + w) * KNN + lane];
    __syncthreads();

    // ---- phase 2: waves 0..3, one head each ----
    if (w < NHEAD) {
        const int h = w;
        const unsigned* T1 = Ksh[2*h];
        const unsigned* T2 = Ksh[2*h+1];

        unsigned c0 = 0, c1 = 0;
        {
            int ia, ja;
            slot_to_ij(lane, ia, ja);
            if (lane < 119) {
                float s = dec_key<9>(T1[ia]) + dec_key<9>(T2[ja]);
                c0 = pack_key<7>(s, lane);
            }
            if (lane + 64 < 119) {
                int ib2, jb2;
                slot_to_ij(lane + 64, ib2, jb2);
                float s = dec_key<9>(T1[ib2]) + dec_key<9>(T2[jb2]);
                c1 = pack_key<7>(s, lane + 64);
            }
        }

        unsigned kk = 0;
        #pragma unroll
        for (int rr = 0; rr < KNN; ++rr) {
            unsigned m  = c0 > c1 ? c0 : c1;
            unsigned bv = wave_umax_bcast(m);
            bool f0 = (c0 == bv);
            bool f1 = (c1 == bv);
            c0 = f0 ? 0u : c0;
            c1 = f1 ? 0u : c1;
            kk = (lane == rr) ? bv : kk;
        }

        unsigned mk = (unsigned)__builtin_amdgcn_readlane((int)kk, 0);
        float mx = dec_key<7>(mk);
        float sv = dec_key<7>(kk);
        float e  = (lane < KNN) ? __expf(sv - mx) : 0.f;
        float Z  = wave_fsum_bcast(e);

        if (lane < KNN) {
            int slot = 127 - (int)(kk & 127u);
            int i, j;
            slot_to_ij(slot, i, j);
            int i1 = 511 - (int)(T1[i] & 511u);
            int i2 = 511 - (int)(T2[j] & 511u);
            wgt_sh[h * KNN + lane] = e / Z;
            idx_sh[h * KNN + lane] = i1 * SUBS + i2;
        }
    }
    __syncthreads();

    // ---- phase 3: weighted gather, 4-way entry split, 8-deep pipeline ----
    const int sub = t >> 7;
    const int c4  = t & 127;
    #define EADDR(i) ((const float4*)(values + (size_t)idx_sh[((i)<<2)|sub] * HIDN) + c4)
    float4 b0 = *EADDR(0), b1 = *EADDR(1), b2 = *EADDR(2), b3 = *EADDR(3);
    float4 b4 = *EADDR(4), b5 = *EADDR(5), b6 = *EADDR(6), b7 = *EADDR(7);
    float4 a0 = make_float4(0.f,0.f,0.f,0.f);
    float4 a1 = make_float4(0.f,0.f,0.f,0.f);
    #define FMA4(acc, wg, v) { acc.x = fmaf(wg, v.x, acc.x); acc.y = fmaf(wg, v.y, acc.y); \
                               acc.z = fmaf(wg, v.z, acc.z); acc.w = fmaf(wg, v.w, acc.w); }
    #define STEPR(bi, ei, acc) { float wg = wgt_sh[((ei)<<2)|sub]; FMA4(acc, wg, bi); bi = *EADDR((ei)+8); }
    #define STEPN(bi, ei, acc) { float wg = wgt_sh[((ei)<<2)|sub]; FMA4(acc, wg, bi); }
    STEPR(b0, 0, a0) STEPR(b1, 1, a1) STEPR(b2, 2, a0) STEPR(b3, 3, a1)
    STEPR(b4, 4, a0) STEPR(b5, 5, a1) STEPR(b6, 6, a0) STEPR(b7, 7, a1)
    STEPR(b0, 8, a0) STEPR(b1, 9, a1) STEPR(b2,10, a0) STEPR(b3,11, a1)
    STEPR(b4,12, a0) STEPR(b5,13, a1) STEPR(b6,14, a0) STEPR(b7,15, a1)
    STEPR(b0,16, a0) STEPR(b1,17, a1) STEPR(b2,18, a0) STEPR(b3,19, a1)
    STEPR(b4,20, a0) STEPR(b5,21, a1) STEPR(b6,22, a0) STEPR(b7,23, a1)
    STEPN(b0,24, a0) STEPN(b1,25, a1) STEPN(b2,26, a0) STEPN(b3,27, a1)
    STEPN(b4,28, a0) STEPN(b5,29, a1) STEPN(b6,30, a0) STEPN(b7,31, a1)
    #undef STEPR
    #undef STEPN
    #undef FMA4
    #undef EADDR
    float4 acc;
    acc.x = a0.x + a1.x; acc.y = a0.y + a1.y;
    acc.z = a0.z + a1.z; acc.w = a0.w + a1.w;

    pacc[sub][c4] = acc;
    __syncthreads();
    if (t < 128) {
        float4 r0 = pacc[0][t], r1 = pacc[1][t], r2 = pacc[2][t], r3 = pacc[3][t];
        float4 r;
        r.x = (r0.x + r1.x) + (r2.x + r3.x);
        r.y = (r0.y + r1.y) + (r2.y + r3.y);
        r.z = (r0.z + r1.z) + (r2.z + r3.z);
        r.w = (r0.w + r1.w) + (r2.w + r3.w);
        ((float4*)(out + (size_t)b * HIDN))[t] = r;
    }
}

extern "C" void kernel_launch(void* const* d_in, const int* in_sizes, int n_in,
                              void* d_out, int out_size, void* d_ws, size_t ws_size,
                              hipStream_t stream)
{
    const float* x      = (const float*)d_in[0];
    const float* W1     = (const float*)d_in[1];
    const float* b1     = (const float*)d_in[2];
    const float* W2     = (const float*)d_in[3];
    const float* b2     = (const float*)d_in[4];
    const float* gamma  = (const float*)d_in[5];
    const float* beta   = (const float*)d_in[6];
    const float* keys   = (const float*)d_in[7];
    const float* values = (const float*)d_in[8];
    float* out = (float*)d_out;

    float* ws    = (float*)d_ws;
    float* part  = ws;                                   // 32*1024
    float* scale = part + (size_t)32 * H2N;              // 1024
    float* shift = scale + H2N;                          // 1024
    float* biasp = shift + H2N;                          // 4096
    unsigned* t_all = (unsigned*)(biasp + 4096);         // 4096*8*32 u32 = 4 MB
    _Float16* xh    = (_Float16*)(t_all + (size_t)NROWS * 8 * KNN);
    _Float16* w1h   = xh  + (size_t)NROWS * HIDN;
    _Float16* w2h   = w1h + (size_t)H1N * HIDN;
    _Float16* h1h   = w2h + (size_t)H2N * H1N;
    _Float16* h2f   = h1h + (size_t)NROWS * H1N;
    _Float16* keysp = h2f + (size_t)NROWS * H2N;         // 4096*128

    // converts
    cvt_f16<<<dim3((NROWS * HIDN) / 1024), 256, 0, stream>>>(x, xh);
    cvt_f16<<<dim3((H1N * HIDN) / 1024), 256, 0, stream>>>(W1, w1h);
    cvt_f16<<<dim3((H2N * H1N) / 1024), 256, 0, stream>>>(W2, w2h);

    // h1 = elu(x @ W1^T + b1)  -> fp16
    gemm_f16<64, 1><<<dim3(NROWS/128, H1N/64), 256, 0, stream>>>(
        xh, w1h, b1, h1h, HIDN, HIDN, HIDN, H1N);
    // h2 = h1 @ W2^T + b2      -> fp16
    gemm_f16<128, 0><<<dim3(NROWS/128, H2N/128), 256, 0, stream>>>(
        h1h, w2h, b2, h2f, H1N, H1N, H1N, H2N);

    // batch-norm stats -> scale/shift
    bn_partial_h<<<dim3(H2N/256, 16), 256, 0, stream>>>(h2f, part);
    bn_finalize<<<dim3(H2N/256), 256, 0, stream>>>(part, gamma, beta, scale, shift);

    // fold affine into keys
    keys_prep<<<dim3(1024), 256, 0, stream>>>(keys, scale, shift, keysp, biasp);

    // fused scores + per-task top-32
    score_topk<<<dim3(NROWS/64, 8), 512, 0, stream>>>(h2f, keysp, biasp, t_all);

    // combine + softmax + weighted gather
    topk_gather<<<dim3(NROWS), 512, 0, stream>>>(t_all, values, out);
}

// Round 11
// 226.475 us; speedup vs baseline: 1.1903x; 1.1903x over previous
//
#include <hip/hip_runtime.h>
#include <math.h>

#define NROWS 4096
#define HIDN  512
#define H1N   256
#define H2N   1024
#define NHEAD 4
#define KDIM  256
#define HALFD 128
#define SUBS  512
#define KNN   32

typedef _Float16 f16x8 __attribute__((ext_vector_type(8)));
typedef _Float16 f16x4v __attribute__((ext_vector_type(4)));
typedef float f32x4  __attribute__((ext_vector_type(4)));

// ---------------- DPP wave reduction helpers ----------------
template<int C>
__device__ __forceinline__ unsigned dpp_umax(unsigned x) {
    unsigned m = (unsigned)__builtin_amdgcn_update_dpp((int)x, (int)x, C, 0xf, 0xf, false);
    return x > m ? x : m;
}
__device__ __forceinline__ unsigned wave_umax_bcast(unsigned x) {
    x = dpp_umax<0x111>(x);
    x = dpp_umax<0x112>(x);
    x = dpp_umax<0x114>(x);
    x = dpp_umax<0x118>(x);
    x = dpp_umax<0x142>(x);
    x = dpp_umax<0x143>(x);
    return (unsigned)__builtin_amdgcn_readlane((int)x, 63);
}
template<int C>
__device__ __forceinline__ float dpp_fadd(float x) {
    int m = __builtin_amdgcn_update_dpp(0, __float_as_int(x), C, 0xf, 0xf, true);
    return x + __int_as_float(m);
}
__device__ __forceinline__ float wave_fsum_bcast(float x) {
    x = dpp_fadd<0x111>(x);
    x = dpp_fadd<0x112>(x);
    x = dpp_fadd<0x114>(x);
    x = dpp_fadd<0x118>(x);
    x = dpp_fadd<0x142>(x);
    x = dpp_fadd<0x143>(x);
    return __int_as_float(__builtin_amdgcn_readlane(__float_as_int(x), 63));
}

template<int IB>
__device__ __forceinline__ unsigned pack_key(float v, int j) {
    unsigned b = __float_as_uint(v);
    unsigned x = (unsigned)((int)b >> 31) | 0x80000000u;
    unsigned k = b ^ x;
    constexpr unsigned LM = (1u << IB) - 1u;
    return (k & ~LM) | (LM - (unsigned)j);
}
template<int IB>
__device__ __forceinline__ float dec_key(unsigned k) {
    constexpr unsigned LM = (1u << IB) - 1u;
    unsigned kv = k & ~LM;
    unsigned x = (~(unsigned)((int)kv >> 31)) | 0x80000000u;
    return __uint_as_float(kv ^ x);
}

__device__ __forceinline__ void slot_to_ij(int s, int& io, int& jo) {
    constexpr int O[32] = {0,32,48,58,66,72,77,81,85,88,91,93,95,97,99,101,
                           103,104,105,106,107,108,109,110,111,112,113,114,115,116,117,118};
    int ii = 0, oo = 0;
    #pragma unroll
    for (int k = 1; k < 32; ++k) {
        bool ge = (s >= O[k]);
        ii += ge ? 1 : 0;
        oo = ge ? O[k] : oo;
    }
    io = ii; jo = s - oo;
}

// ---------------- fp32 -> fp16 convert ----------------
__global__ __launch_bounds__(256)
void cvt_f16(const float* __restrict__ in, _Float16* __restrict__ out)
{
    int i = (blockIdx.x * 256 + threadIdx.x) * 4;
    float4 v = *(const float4*)&in[i];
    f16x4v o = {(_Float16)v.x, (_Float16)v.y, (_Float16)v.z, (_Float16)v.w};
    *(f16x4v*)&out[i] = o;
}

// ---------------- fp16 MFMA GEMM: C = act(A(M,K) @ B(N,K)^T + bias), fp16 out ----------------
template<int BN, int ACT>
__global__ __launch_bounds__(256)
void gemm_f16(const _Float16* __restrict__ A, const _Float16* __restrict__ B,
              const float* __restrict__ bias, _Float16* __restrict__ C,
              int K, int lda, int ldb, int ldc)
{
    constexpr int WR = (BN == 128) ? 2 : 4;
    constexpr int WM = 128 / WR;
    constexpr int MT = WM / 16;
    constexpr int NT = 4;

    __shared__ _Float16 As[128 * 64];
    __shared__ _Float16 Bs[BN * 64];

    const int t    = threadIdx.x;
    const int m0   = blockIdx.x * 128, n0 = blockIdx.y * BN;
    const int lane = t & 63, wv = t >> 6;
    const int wr   = (BN == 128) ? (wv >> 1) : wv;
    const int wc   = (BN == 128) ? (wv & 1) : 0;
    const int sr   = t >> 3;
    const int sce  = (t & 7) * 8;
    const int swz  = sce * 2;

    const f32x4 fz = {0.f, 0.f, 0.f, 0.f};
    f32x4 acc[MT][NT];
    #pragma unroll
    for (int mt = 0; mt < MT; ++mt)
        #pragma unroll
        for (int nt = 0; nt < NT; ++nt) acc[mt][nt] = fz;

    for (int kb = 0; kb < K; kb += 64) {
        #pragma unroll
        for (int i = 0; i < 4; ++i) {
            int r = sr + 32 * i;
            uint4 v = *(const uint4*)&A[(size_t)(m0 + r) * lda + kb + sce];
            *(uint4*)((char*)As + r * 128 + (swz ^ ((r & 7) << 4))) = v;
        }
        #pragma unroll
        for (int i = 0; i < BN / 32; ++i) {
            int r = sr + 32 * i;
            uint4 v = *(const uint4*)&B[(size_t)(n0 + r) * ldb + kb + sce];
            *(uint4*)((char*)Bs + r * 128 + (swz ^ ((r & 7) << 4))) = v;
        }
        __syncthreads();
        #pragma unroll
        for (int ks = 0; ks < 2; ++ks) {
            const int kbyte = ks * 64 + (lane >> 4) * 16;
            f16x8 ah[MT], bf[NT];
            #pragma unroll
            for (int mt = 0; mt < MT; ++mt) {
                int r = wr * WM + mt * 16 + (lane & 15);
                ah[mt] = *(const f16x8*)((const char*)As + r * 128 + (kbyte ^ ((r & 7) << 4)));
            }
            #pragma unroll
            for (int nt = 0; nt < NT; ++nt) {
                int r = wc * 64 + nt * 16 + (lane & 15);
                bf[nt] = *(const f16x8*)((const char*)Bs + r * 128 + (kbyte ^ ((r & 7) << 4)));
            }
            #pragma unroll
            for (int mt = 0; mt < MT; ++mt)
                #pragma unroll
                for (int nt = 0; nt < NT; ++nt)
                    acc[mt][nt] = __builtin_amdgcn_mfma_f32_16x16x32_f16(ah[mt], bf[nt], acc[mt][nt], 0, 0, 0);
        }
        __syncthreads();
    }

    #pragma unroll
    for (int mt = 0; mt < MT; ++mt) {
        #pragma unroll
        for (int nt = 0; nt < NT; ++nt) {
            int col = n0 + wc * 64 + nt * 16 + (lane & 15);
            float bz = bias[col];
            #pragma unroll
            for (int j = 0; j < 4; ++j) {
                int row = m0 + wr * WM + mt * 16 + (lane >> 4) * 4 + j;
                float v = acc[mt][nt][j] + bz;
                if (ACT) v = v > 0.f ? v : expm1f(v);
                C[(size_t)row * ldc + col] = (_Float16)v;
            }
        }
    }
}

// ---------------- BatchNorm stats (fp16 h2) ----------------
__global__ __launch_bounds__(256)
void bn_partial_h(const _Float16* __restrict__ h2f, float* __restrict__ part)
{
    int col = blockIdx.x * 256 + threadIdx.x;
    int r0  = blockIdx.y * 256;
    float s = 0.f, q = 0.f;
    for (int rr = r0; rr < r0 + 256; ++rr) {
        float v = (float)h2f[(size_t)rr * H2N + col];
        s += v; q += v * v;
    }
    part[(size_t)blockIdx.y * H2N + col] = s;
    part[(size_t)16 * H2N + (size_t)blockIdx.y * H2N + col] = q;
}

__global__ __launch_bounds__(256)
void bn_finalize(const float* __restrict__ part, const float* __restrict__ gamma,
                 const float* __restrict__ beta, float* __restrict__ scale,
                 float* __restrict__ shift)
{
    int col = blockIdx.x * 256 + threadIdx.x;
    float s = 0.f, q = 0.f;
    for (int c = 0; c < 16; ++c) {
        s += part[(size_t)c * H2N + col];
        q += part[(size_t)16 * H2N + (size_t)c * H2N + col];
    }
    float mu  = s * (1.f / NROWS);
    float var = q * (1.f / NROWS) - mu * mu;
    float sc  = gamma[col] / sqrtf(var + 1e-5f);
    scale[col] = sc;
    shift[col] = beta[col] - mu * sc;
}

// ---------------- fold BN affine into keys ----------------
__global__ __launch_bounds__(256)
void keys_prep(const float* __restrict__ keys, const float* __restrict__ scale,
               const float* __restrict__ shift, _Float16* __restrict__ keysp,
               float* __restrict__ biasp)
{
    const int gid  = blockIdx.x * 4 + (threadIdx.x >> 6);   // 0..4095
    const int lane = threadIdx.x & 63;
    const int z    = gid >> 9;
    const float* krow = keys + (size_t)gid * HALFD;
    const int d0 = lane * 2;
    float k0 = krow[d0], k1 = krow[d0 + 1];
    float sc0 = scale[z * HALFD + d0], sc1 = scale[z * HALFD + d0 + 1];
    float sh0 = shift[z * HALFD + d0], sh1 = shift[z * HALFD + d0 + 1];
    _Float16 p0 = (_Float16)(sc0 * k0), p1 = (_Float16)(sc1 * k1);
    unsigned u;
    {
        union { _Float16 h[2]; unsigned u; } cvt;
        cvt.h[0] = p0; cvt.h[1] = p1;
        u = cvt.u;
    }
    *(unsigned*)&keysp[(size_t)gid * HALFD + d0] = u;
    float dot = wave_fsum_bcast(k0 * sh0 + k1 * sh1);
    if (lane == 0) biasp[gid] = dot;
}

// ---------------- Score MFMA (fp16 in, fp16 out, bias added) ----------------
__global__ __launch_bounds__(256)
void score_f16(const _Float16* __restrict__ h2f, const _Float16* __restrict__ keysp,
               const float* __restrict__ biasp, _Float16* __restrict__ s1h,
               _Float16* __restrict__ s2h)
{
    __shared__ _Float16 As[128 * 64];
    __shared__ _Float16 Bs[128 * 64];

    const int t    = threadIdx.x;
    const int z    = blockIdx.z;
    const int m0   = blockIdx.x * 128, n0 = blockIdx.y * 128;
    const int lane = t & 63, wv = t >> 6;
    const int wr   = wv >> 1, wc = wv & 1;
    const int sr   = t >> 3;
    const int sce  = (t & 7) * 8;
    const int swz  = sce * 2;

    const _Float16* A = h2f + z * HALFD;                      // lda = 1024
    const _Float16* B = keysp + (size_t)z * SUBS * HALFD;     // (512,128)
    _Float16* outb = (z & 1) ? s2h : s1h;
    const int hd = z >> 1;

    const f32x4 fz = {0.f, 0.f, 0.f, 0.f};
    f32x4 acc[4][4];
    #pragma unroll
    for (int mt = 0; mt < 4; ++mt)
        #pragma unroll
        for (int nt = 0; nt < 4; ++nt) acc[mt][nt] = fz;

    for (int kb = 0; kb < HALFD; kb += 64) {
        #pragma unroll
        for (int i = 0; i < 4; ++i) {
            int r = sr + 32 * i;
            uint4 v = *(const uint4*)&A[(size_t)(m0 + r) * H2N + kb + sce];
            *(uint4*)((char*)As + r * 128 + (swz ^ ((r & 7) << 4))) = v;
        }
        #pragma unroll
        for (int i = 0; i < 4; ++i) {
            int r = sr + 32 * i;
            uint4 v = *(const uint4*)&B[(size_t)(n0 + r) * HALFD + kb + sce];
            *(uint4*)((char*)Bs + r * 128 + (swz ^ ((r & 7) << 4))) = v;
        }
        __syncthreads();
        #pragma unroll
        for (int ks = 0; ks < 2; ++ks) {
            const int kbyte = ks * 64 + (lane >> 4) * 16;
            f16x8 af[4], bf[4];
            #pragma unroll
            for (int mt = 0; mt < 4; ++mt) {
                int r = wr * 64 + mt * 16 + (lane & 15);
                af[mt] = *(const f16x8*)((const char*)As + r * 128 + (kbyte ^ ((r & 7) << 4)));
            }
            #pragma unroll
            for (int nt = 0; nt < 4; ++nt) {
                int r = wc * 64 + nt * 16 + (lane & 15);
                bf[nt] = *(const f16x8*)((const char*)Bs + r * 128 + (kbyte ^ ((r & 7) << 4)));
            }
            #pragma unroll
            for (int mt = 0; mt < 4; ++mt)
                #pragma unroll
                for (int nt = 0; nt < 4; ++nt)
                    acc[mt][nt] = __builtin_amdgcn_mfma_f32_16x16x32_f16(af[mt], bf[nt], acc[mt][nt], 0, 0, 0);
        }
        __syncthreads();
    }

    #pragma unroll
    for (int mt = 0; mt < 4; ++mt) {
        #pragma unroll
        for (int nt = 0; nt < 4; ++nt) {
            int col = n0 + wc * 64 + nt * 16 + (lane & 15);
            float bz = biasp[z * SUBS + col];
            #pragma unroll
            for (int j = 0; j < 4; ++j) {
                int row = m0 + wr * 64 + mt * 16 + (lane >> 4) * 4 + j;
                outb[((size_t)row * NHEAD + hd) * SUBS + col] = (_Float16)(acc[mt][nt][j] + bz);
            }
        }
    }
}

// ---------------- Fused top-k + combine + softmax + gather ----------------
__global__ __launch_bounds__(512)
void topk_gather(const _Float16* __restrict__ s1h, const _Float16* __restrict__ s2h,
                 const float* __restrict__ values, float* __restrict__ out)
{
    const int b    = blockIdx.x;
    const int t    = threadIdx.x;
    const int w    = t >> 6;
    const int lane = t & 63;

    __shared__ unsigned Ksh[8][KNN];
    __shared__ float wgt_sh[NHEAD * KNN];
    __shared__ int   idx_sh[NHEAD * KNN];
    __shared__ float4 pacc[4][128];

    // ---- phase 1: one wave per (head,half) task, fp16 scores ----
    {
        const int head = w >> 1, half = w & 1;
        const _Float16* srow = (half ? s2h : s1h) + ((size_t)b * NHEAD + head) * SUBS;
        f16x8 v = *(const f16x8*)&srow[lane * 8];
        const int j0 = lane * 8;
        unsigned k0 = pack_key<9>((float)v[0], j0+0), k1 = pack_key<9>((float)v[1], j0+1);
        unsigned k2 = pack_key<9>((float)v[2], j0+2), k3 = pack_key<9>((float)v[3], j0+3);
        unsigned k4 = pack_key<9>((float)v[4], j0+4), k5 = pack_key<9>((float)v[5], j0+5);
        unsigned k6 = pack_key<9>((float)v[6], j0+6), k7 = pack_key<9>((float)v[7], j0+7);

        #define CEU(a,b) { unsigned _mx = (a)>(b)?(a):(b); unsigned _mn = (a)>(b)?(b):(a); (a)=_mx; (b)=_mn; }
        CEU(k0,k1) CEU(k2,k3) CEU(k4,k5) CEU(k6,k7)
        CEU(k0,k2) CEU(k1,k3) CEU(k4,k6) CEU(k5,k7)
        CEU(k1,k2) CEU(k5,k6)
        CEU(k0,k4) CEU(k1,k5) CEU(k2,k6) CEU(k3,k7)
        CEU(k2,k4) CEU(k3,k5)
        CEU(k1,k2) CEU(k3,k4) CEU(k5,k6)
        #undef CEU

        unsigned kk = 0;
        #pragma unroll
        for (int rr = 0; rr < KNN; ++rr) {
            unsigned bv = wave_umax_bcast(k0);
            bool win = (k0 == bv);
            k0 = win ? k1 : k0;
            k1 = win ? k2 : k1;
            k2 = win ? k3 : k2;
            k3 = win ? k4 : k3;
            k4 = win ? k5 : k4;
            k5 = win ? k6 : k5;
            k6 = win ? k7 : k6;
            k7 = win ? 0u : k7;
            kk = (lane == rr) ? bv : kk;
        }
        if (lane < KNN) Ksh[w][lane] = kk;
    }
    __syncthreads();

    // ---- phase 2: waves 0..3, one head each ----
    if (w < NHEAD) {
        const int h = w;
        const unsigned* T1 = Ksh[2*h];
        const unsigned* T2 = Ksh[2*h+1];

        unsigned c0 = 0, c1 = 0;
        {
            int ia, ja;
            slot_to_ij(lane, ia, ja);
            if (lane < 119) {
                float s = dec_key<9>(T1[ia]) + dec_key<9>(T2[ja]);
                c0 = pack_key<7>(s, lane);
            }
            if (lane + 64 < 119) {
                int ib2, jb2;
                slot_to_ij(lane + 64, ib2, jb2);
                float s = dec_key<9>(T1[ib2]) + dec_key<9>(T2[jb2]);
                c1 = pack_key<7>(s, lane + 64);
            }
        }

        unsigned kk = 0;
        #pragma unroll
        for (int rr = 0; rr < KNN; ++rr) {
            unsigned m  = c0 > c1 ? c0 : c1;
            unsigned bv = wave_umax_bcast(m);
            bool f0 = (c0 == bv);
            bool f1 = (c1 == bv);
            c0 = f0 ? 0u : c0;
            c1 = f1 ? 0u : c1;
            kk = (lane == rr) ? bv : kk;
        }

        unsigned mk = (unsigned)__builtin_amdgcn_readlane((int)kk, 0);
        float mx = dec_key<7>(mk);
        float sv = dec_key<7>(kk);
        float e  = (lane < KNN) ? __expf(sv - mx) : 0.f;
        float Z  = wave_fsum_bcast(e);

        if (lane < KNN) {
            int slot = 127 - (int)(kk & 127u);
            int i, j;
            slot_to_ij(slot, i, j);
            int i1 = 511 - (int)(T1[i] & 511u);
            int i2 = 511 - (int)(T2[j] & 511u);
            wgt_sh[h * KNN + lane] = e / Z;
            idx_sh[h * KNN + lane] = i1 * SUBS + i2;
        }
    }
    __syncthreads();

    // ---- phase 3: weighted gather, 4-way entry split, 8-deep pipeline ----
    const int sub = t >> 7;
    const int c4  = t & 127;
    #define EADDR(i) ((const float4*)(values + (size_t)idx_sh[((i)<<2)|sub] * HIDN) + c4)
    float4 b0 = *EADDR(0), b1 = *EADDR(1), b2 = *EADDR(2), b3 = *EADDR(3);
    float4 b4 = *EADDR(4), b5 = *EADDR(5), b6 = *EADDR(6), b7 = *EADDR(7);
    float4 a0 = make_float4(0.f,0.f,0.f,0.f);
    float4 a1 = make_float4(0.f,0.f,0.f,0.f);
    #define FMA4(acc, wg, v) { acc.x = fmaf(wg, v.x, acc.x); acc.y = fmaf(wg, v.y, acc.y); \
                               acc.z = fmaf(wg, v.z, acc.z); acc.w = fmaf(wg, v.w, acc.w); }
    #define STEPR(bi, ei, acc) { float wg = wgt_sh[((ei)<<2)|sub]; FMA4(acc, wg, bi); bi = *EADDR((ei)+8); }
    #define STEPN(bi, ei, acc) { float wg = wgt_sh[((ei)<<2)|sub]; FMA4(acc, wg, bi); }
    STEPR(b0, 0, a0) STEPR(b1, 1, a1) STEPR(b2, 2, a0) STEPR(b3, 3, a1)
    STEPR(b4, 4, a0) STEPR(b5, 5, a1) STEPR(b6, 6, a0) STEPR(b7, 7, a1)
    STEPR(b0, 8, a0) STEPR(b1, 9, a1) STEPR(b2,10, a0) STEPR(b3,11, a1)
    STEPR(b4,12, a0) STEPR(b5,13, a1) STEPR(b6,14, a0) STEPR(b7,15, a1)
    STEPR(b0,16, a0) STEPR(b1,17, a1) STEPR(b2,18, a0) STEPR(b3,19, a1)
    STEPR(b4,20, a0) STEPR(b5,21, a1) STEPR(b6,22, a0) STEPR(b7,23, a1)
    STEPN(b0,24, a0) STEPN(b1,25, a1) STEPN(b2,26, a0) STEPN(b3,27, a1)
    STEPN(b4,28, a0) STEPN(b5,29, a1) STEPN(b6,30, a0) STEPN(b7,31, a1)
    #undef STEPR
    #undef STEPN
    #undef FMA4
    #undef EADDR
    float4 acc;
    acc.x = a0.x + a1.x; acc.y = a0.y + a1.y;
    acc.z = a0.z + a1.z; acc.w = a0.w + a1.w;

    pacc[sub][c4] = acc;
    __syncthreads();
    if (t < 128) {
        float4 r0 = pacc[0][t], r1 = pacc[1][t], r2 = pacc[2][t], r3 = pacc[3][t];
        float4 r;
        r.x = (r0.x + r1.x) + (r2.x + r3.x);
        r.y = (r0.y + r1.y) + (r2.y + r3.y);
        r.z = (r0.z + r1.z) + (r2.z + r3.z);
        r.w = (r0.w + r1.w) + (r2.w + r3.w);
        ((float4*)(out + (size_t)b * HIDN))[t] = r;
    }
}

extern "C" void kernel_launch(void* const* d_in, const int* in_sizes, int n_in,
                              void* d_out, int out_size, void* d_ws, size_t ws_size,
                              hipStream_t stream)
{
    const float* x      = (const float*)d_in[0];
    const float* W1     = (const float*)d_in[1];
    const float* b1     = (const float*)d_in[2];
    const float* W2     = (const float*)d_in[3];
    const float* b2     = (const float*)d_in[4];
    const float* gamma  = (const float*)d_in[5];
    const float* beta   = (const float*)d_in[6];
    const float* keys   = (const float*)d_in[7];
    const float* values = (const float*)d_in[8];
    float* out = (float*)d_out;

    float* ws    = (float*)d_ws;
    float* part  = ws;                                   // 32*1024
    float* scale = part + (size_t)32 * H2N;              // 1024
    float* shift = scale + H2N;                          // 1024
    float* biasp = shift + H2N;                          // 4096
    _Float16* s1h   = (_Float16*)(biasp + 4096);         // 4096*4*512 fp16
    _Float16* s2h   = s1h + (size_t)NROWS * NHEAD * SUBS;
    _Float16* xh    = s2h + (size_t)NROWS * NHEAD * SUBS;
    _Float16* w1h   = xh  + (size_t)NROWS * HIDN;
    _Float16* w2h   = w1h + (size_t)H1N * HIDN;
    _Float16* h1h   = w2h + (size_t)H2N * H1N;
    _Float16* h2f   = h1h + (size_t)NROWS * H1N;
    _Float16* keysp = h2f + (size_t)NROWS * H2N;         // 4096*128

    // converts
    cvt_f16<<<dim3((NROWS * HIDN) / 1024), 256, 0, stream>>>(x, xh);
    cvt_f16<<<dim3((H1N * HIDN) / 1024), 256, 0, stream>>>(W1, w1h);
    cvt_f16<<<dim3((H2N * H1N) / 1024), 256, 0, stream>>>(W2, w2h);

    // h1 = elu(x @ W1^T + b1)  -> fp16
    gemm_f16<64, 1><<<dim3(NROWS/128, H1N/64), 256, 0, stream>>>(
        xh, w1h, b1, h1h, HIDN, HIDN, HIDN, H1N);
    // h2 = h1 @ W2^T + b2      -> fp16
    gemm_f16<128, 0><<<dim3(NROWS/128, H2N/128), 256, 0, stream>>>(
        h1h, w2h, b2, h2f, H1N, H1N, H1N, H2N);

    // batch-norm stats -> scale/shift
    bn_partial_h<<<dim3(H2N/256, 16), 256, 0, stream>>>(h2f, part);
    bn_finalize<<<dim3(H2N/256), 256, 0, stream>>>(part, gamma, beta, scale, shift);

    // fold affine into keys
    keys_prep<<<dim3(1024), 256, 0, stream>>>(keys, scale, shift, keysp, biasp);

    // scores (fp16 out)
    score_f16<<<dim3(NROWS/128, SUBS/128, NHEAD*2), 256, 0, stream>>>(h2f, keysp, biasp, s1h, s2h);

    // top-k + softmax + weighted gather
    topk_gather<<<dim3(NROWS), 512, 0, stream>>>(s1h, s2h, values, out);
}